// Round 12
// baseline (433.327 us; speedup 1.0000x reference)
//
#include <hip/hip_runtime.h>
#include <hip/hip_bf16.h>
#include <math.h>

// ---------------- problem constants ----------------
constexpr int Nn  = 10000;     // nodes
constexpr int Ed  = 320000;    // edges (before self-loops)
constexpr int DIN = 256;
constexpr float NEG = 0.2f;    // leaky-relu slope

// ---------------- scratch layout inside d_out (float offsets) ----------------
// d_out = [adj 1e8][mu 320000][log_var 320000]. The adj region is free scratch
// until k_adjm, which fully overwrites it (round-3 lesson: nothing may live in
// the adj region once k_adjm starts).
constexpr size_t OFF_XL  = 0;          // [N,256] bf16 (gather operand)
constexpr size_t OFF_XR  = 2560000;    // [N,256] f32
constexpr size_t OFF_H   = 5120000;    // [N,256] f32
constexpr size_t OFF_XSL = 7680000;    // [N,64]  bf16 (xl_mu | xl_lv)
constexpr size_t OFF_XSR = 8320000;    // [N,64]  f32
constexpr size_t OFF_WLC = 8960000;    // [256,64]
constexpr size_t OFF_WRC = 8976384;    // [256,64]
constexpr size_t OFF_BLC = 8992768;    // [64]
constexpr size_t OFF_BRC = 8992832;    // [64]
constexpr size_t OFF_ATT = 8992896;    // [64]
constexpr size_t OFF_BOC = 8992960;    // [64]
constexpr size_t OFF_INT = 9000000;    // int area base
constexpr int I_DEG = 0;               // [N]
constexpr int I_ROW = 16384;           // [N+1]
constexpr int I_CUR = 32768;           // [N]
constexpr int I_CSR = 49152;           // [E+N]
static_assert(OFF_INT + (I_CSR + Ed + Nn + 4) < 100000000, "scratch fits in adj region");

// ---------------- bf16 helpers (RNE) ----------------
__device__ __forceinline__ unsigned short f2bf(float x) {
    unsigned int u = __float_as_uint(x);
    unsigned int r = (u + 0x7FFFu + ((u >> 16) & 1u)) >> 16;
    return (unsigned short)r;
}
__device__ __forceinline__ float bf2f(unsigned short b) {
    return __uint_as_float(((unsigned int)b) << 16);
}

typedef short bf16x8 __attribute__((ext_vector_type(8)));
typedef float f32x4  __attribute__((ext_vector_type(4)));

// ---------------- CSR build ----------------
__global__ void k_init_deg(int* deg, int n) {
    int i = blockIdx.x * blockDim.x + threadIdx.x;
    if (i < n) deg[i] = 1;   // self-loop
}

__global__ void k_count(const int* __restrict__ dst, int* deg, int e) {
    int i = blockIdx.x * blockDim.x + threadIdx.x;
    if (i < e) atomicAdd(&deg[dst[i]], 1);
}

__global__ void k_scan(const int* __restrict__ deg, int* row_ptr, int* cursor, int n) {
    __shared__ int sums[256];
    int t = threadIdx.x;
    int chunk = (n + 255) / 256;
    int start = t * chunk, end = min(start + chunk, n);
    int s = 0;
    for (int i = start; i < end; ++i) s += deg[i];
    sums[t] = s;
    __syncthreads();
    for (int off = 1; off < 256; off <<= 1) {
        int v = (t >= off) ? sums[t - off] : 0;
        __syncthreads();
        sums[t] += v;
        __syncthreads();
    }
    int run = sums[t] - s;  // exclusive prefix
    for (int i = start; i < end; ++i) { row_ptr[i] = run; cursor[i] = run; run += deg[i]; }
    if (t == 255) row_ptr[n] = sums[255];
}

__global__ void k_scatter(const int* __restrict__ src, const int* __restrict__ dst,
                          int* cursor, int* csr, int e, int n) {
    int i = blockIdx.x * blockDim.x + threadIdx.x;
    if (i < e) {
        int d = dst[i];
        int pos = atomicAdd(&cursor[d], 1);
        csr[pos] = src[i];
    } else if (i < e + n) {
        int v = i - e;                        // self-loop
        int pos = atomicAdd(&cursor[v], 1);
        csr[pos] = v;
    }
}

// ---------------- fused dual GEMM: outL/outR = A @ {WL,WR} + bias -------------
// Round-9-verified staging/index scheme, re-tiled this round to cut the LDS
// read:FMA ratio: 128-row tile, 8 rows x 4 cols x 2 matrices per thread ->
// 4 b128 LDS reads per 64 FMAs (was 3 per 32). A-broadcast and contiguous
// W reads are conflict-free. outL bf16 (GAT gather operand), outR f32.
template <int NC>
__global__ __launch_bounds__(256) void k_gemm2(const float* __restrict__ A,
                                               const float* __restrict__ WL,
                                               const float* __restrict__ biasL,
                                               unsigned short* __restrict__ outL,
                                               const float* __restrict__ WR,
                                               const float* __restrict__ biasR,
                                               float* __restrict__ outR,
                                               int M) {
    constexpr int K = 256;
    __shared__ float As[32][132];   // [k][m], 128 rows + pad 4 (16B-aligned rows)
    __shared__ float WsL[32][64];   // [k][n]
    __shared__ float WsR[32][64];
    int tid = threadIdx.x;
    int tx = tid & 15, ty = tid >> 4;            // tx: 4 cols, ty: 8 rows
    int m0 = blockIdx.x * 128, n0 = blockIdx.y * 64;
    float accL[8][4] = {}, accR[8][4] = {};
    int am = tid >> 1, akb = (tid & 1) * 16;     // A-tile: row am (0..127), k-chunk akb..+15
    int wk = tid >> 3, wnb = (tid & 7) * 8;      // W-tile: k-row wk, n-chunk wnb..+7
    const bool arow_ok = (m0 + am) < M;
    const float* Aptr  = A  + (size_t)(m0 + am) * K + akb;
    const float* WLptr = WL + (size_t)wk * NC + n0 + wnb;
    const float* WRptr = WR + (size_t)wk * NC + n0 + wnb;

    for (int k0 = 0; k0 < K; k0 += 32) {
        float4 aq[4] = {{0,0,0,0},{0,0,0,0},{0,0,0,0},{0,0,0,0}};
        if (arow_ok) {
            #pragma unroll
            for (int q = 0; q < 4; ++q)
                aq[q] = *(const float4*)(Aptr + k0 + q * 4);
        }
        float4 wl0 = *(const float4*)(WLptr + (size_t)k0 * NC);
        float4 wl1 = *(const float4*)(WLptr + (size_t)k0 * NC + 4);
        float4 wr0 = *(const float4*)(WRptr + (size_t)k0 * NC);
        float4 wr1 = *(const float4*)(WRptr + (size_t)k0 * NC + 4);
        __syncthreads();   // protect previous iteration's LDS reads
        #pragma unroll
        for (int q = 0; q < 4; ++q) {
            As[akb + q * 4 + 0][am] = aq[q].x;
            As[akb + q * 4 + 1][am] = aq[q].y;
            As[akb + q * 4 + 2][am] = aq[q].z;
            As[akb + q * 4 + 3][am] = aq[q].w;
        }
        *(float4*)&WsL[wk][wnb]     = wl0;
        *(float4*)&WsL[wk][wnb + 4] = wl1;
        *(float4*)&WsR[wk][wnb]     = wr0;
        *(float4*)&WsR[wk][wnb + 4] = wr1;
        __syncthreads();
        #pragma unroll
        for (int k = 0; k < 32; ++k) {
            float4 a0 = *(const float4*)&As[k][ty * 8];
            float4 a1 = *(const float4*)&As[k][ty * 8 + 4];
            float4 bl = *(const float4*)&WsL[k][tx * 4];
            float4 br = *(const float4*)&WsR[k][tx * 4];
            float av[8]  = {a0.x, a0.y, a0.z, a0.w, a1.x, a1.y, a1.z, a1.w};
            float blv[4] = {bl.x, bl.y, bl.z, bl.w};
            float brv[4] = {br.x, br.y, br.z, br.w};
            #pragma unroll
            for (int i2 = 0; i2 < 8; ++i2)
                #pragma unroll
                for (int j2 = 0; j2 < 4; ++j2) {
                    accL[i2][j2] = fmaf(av[i2], blv[j2], accL[i2][j2]);
                    accR[i2][j2] = fmaf(av[i2], brv[j2], accR[i2][j2]);
                }
        }
    }
    #pragma unroll
    for (int i2 = 0; i2 < 8; ++i2) {
        int row = m0 + ty * 8 + i2;
        if (row < M) {
            int col = n0 + tx * 4;
            // L (bf16)
            ushort4 s;
            s.x = f2bf(accL[i2][0] + biasL[col + 0]);
            s.y = f2bf(accL[i2][1] + biasL[col + 1]);
            s.z = f2bf(accL[i2][2] + biasL[col + 2]);
            s.w = f2bf(accL[i2][3] + biasL[col + 3]);
            *(ushort4*)&outL[(size_t)row * NC + col] = s;
            // R (f32)
            float4 o;
            o.x = accR[i2][0] + biasR[col + 0];
            o.y = accR[i2][1] + biasR[col + 1];
            o.z = accR[i2][2] + biasR[col + 2];
            o.w = accR[i2][3] + biasR[col + 3];
            *(float4*)&outR[(size_t)row * NC + col] = o;
        }
    }
}

// ---------------- GATv2 aggregation, F=256 H=4 C=64 (lane = 4 channels) ----------
// xl is bf16 (512B/edge gather). Round-11-verified 4-edge-unroll structure.
__device__ __forceinline__ float lrelu(float x) { return x > 0.f ? x : NEG * x; }

template <bool DO_ELU>
__global__ __launch_bounds__(256) void k_gat4(const unsigned short* __restrict__ xl,
                                              const float* __restrict__ xr,
                                              const float* __restrict__ att,
                                              const float* __restrict__ bo,
                                              const int* __restrict__ row_ptr,
                                              const int* __restrict__ csr,
                                              float* __restrict__ out, int n) {
    int lane = threadIdx.x & 63;
    int node = (blockIdx.x * blockDim.x + threadIdx.x) >> 6;
    if (node >= n) return;
    int f = lane * 4;
    float4 xrr  = *(const float4*)&xr[(size_t)node * 256 + f];
    float4 attr = *(const float4*)&att[f];
    float m = -INFINITY, d = 0.f;
    float4 acc = {0.f, 0.f, 0.f, 0.f};

    int e0 = row_ptr[node], e1 = row_ptr[node + 1];
    int e = e0;
    for (; e + 3 < e1; e += 4) {
        int ja = csr[e],     jb = csr[e + 1];
        int jc = csr[e + 2], jd = csr[e + 3];
        ushort4 ua = *(const ushort4*)&xl[(size_t)ja * 256 + f];
        ushort4 ub = *(const ushort4*)&xl[(size_t)jb * 256 + f];
        ushort4 uc = *(const ushort4*)&xl[(size_t)jc * 256 + f];
        ushort4 ud = *(const ushort4*)&xl[(size_t)jd * 256 + f];
        float4 va = {bf2f(ua.x), bf2f(ua.y), bf2f(ua.z), bf2f(ua.w)};
        float4 vb = {bf2f(ub.x), bf2f(ub.y), bf2f(ub.z), bf2f(ub.w)};
        float4 vc = {bf2f(uc.x), bf2f(uc.y), bf2f(uc.z), bf2f(uc.w)};
        float4 vd = {bf2f(ud.x), bf2f(ud.y), bf2f(ud.z), bf2f(ud.w)};
        float ta = attr.x * lrelu(va.x + xrr.x) + attr.y * lrelu(va.y + xrr.y)
                 + attr.z * lrelu(va.z + xrr.z) + attr.w * lrelu(va.w + xrr.w);
        float tb = attr.x * lrelu(vb.x + xrr.x) + attr.y * lrelu(vb.y + xrr.y)
                 + attr.z * lrelu(vb.z + xrr.z) + attr.w * lrelu(vb.w + xrr.w);
        float tc = attr.x * lrelu(vc.x + xrr.x) + attr.y * lrelu(vc.y + xrr.y)
                 + attr.z * lrelu(vc.z + xrr.z) + attr.w * lrelu(vc.w + xrr.w);
        float td = attr.x * lrelu(vd.x + xrr.x) + attr.y * lrelu(vd.y + xrr.y)
                 + attr.z * lrelu(vd.z + xrr.z) + attr.w * lrelu(vd.w + xrr.w);
        #pragma unroll
        for (int mask = 1; mask <= 8; mask <<= 1) {
            ta += __shfl_xor(ta, mask, 64);
            tb += __shfl_xor(tb, mask, 64);
            tc += __shfl_xor(tc, mask, 64);
            td += __shfl_xor(td, mask, 64);
        }
        float mn = fmaxf(fmaxf(m, fmaxf(ta, tb)), fmaxf(tc, td));
        float sc = __expf(m - mn);         // 1 when m == mn; 0 when m == -inf
        float pa = __expf(ta - mn), pb = __expf(tb - mn);
        float pc = __expf(tc - mn), pd = __expf(td - mn);
        d = d * sc + pa + pb + pc + pd;
        acc.x = acc.x * sc + pa * va.x + pb * vb.x + pc * vc.x + pd * vd.x;
        acc.y = acc.y * sc + pa * va.y + pb * vb.y + pc * vc.y + pd * vd.y;
        acc.z = acc.z * sc + pa * va.z + pb * vb.z + pc * vc.z + pd * vd.z;
        acc.w = acc.w * sc + pa * va.w + pb * vb.w + pc * vc.w + pd * vd.w;
        m = mn;
    }
    for (; e < e1; ++e) {
        int j = csr[e];
        ushort4 u = *(const ushort4*)&xl[(size_t)j * 256 + f];
        float4 v = {bf2f(u.x), bf2f(u.y), bf2f(u.z), bf2f(u.w)};
        float t = attr.x * lrelu(v.x + xrr.x) + attr.y * lrelu(v.y + xrr.y)
                + attr.z * lrelu(v.z + xrr.z) + attr.w * lrelu(v.w + xrr.w);
        #pragma unroll
        for (int mask = 1; mask <= 8; mask <<= 1) t += __shfl_xor(t, mask, 64);
        float mn = fmaxf(m, t);
        float sc = __expf(m - mn), p = __expf(t - mn);
        d = d * sc + p;
        acc.x = acc.x * sc + p * v.x;
        acc.y = acc.y * sc + p * v.y;
        acc.z = acc.z * sc + p * v.z;
        acc.w = acc.w * sc + p * v.w;
        m = mn;
    }
    float inv = 1.f / (d + 1e-16f);
    float4 bo4 = *(const float4*)&bo[f];
    float4 o;
    o.x = acc.x * inv + bo4.x;
    o.y = acc.y * inv + bo4.y;
    o.z = acc.z * inv + bo4.z;
    o.w = acc.w * inv + bo4.w;
    if (DO_ELU) {
        o.x = o.x > 0.f ? o.x : expm1f(o.x);
        o.y = o.y > 0.f ? o.y : expm1f(o.y);
        o.z = o.z > 0.f ? o.z : expm1f(o.z);
        o.w = o.w > 0.f ? o.w : expm1f(o.w);
    }
    *(float4*)&out[(size_t)node * 256 + f] = o;
}

// ---------------- mu|lv GAT (H=2,C=32,F=64) + fused reparameterize ------------
// Round-9-verified. Lanes 0-31 hold mu_c, lanes 32-63 hold lv_c; shfl brings
// lv down; lane<32 computes z and writes split-bf16 zhi/zlo (skipped if null).
__global__ __launch_bounds__(256) void k_gatz(const unsigned short* __restrict__ xl,
                                              const float* __restrict__ xr,
                                              const float* __restrict__ att,
                                              const float* __restrict__ bo,
                                              const int* __restrict__ row_ptr,
                                              const int* __restrict__ csr,
                                              const float* __restrict__ eps,
                                              float* __restrict__ out0,
                                              float* __restrict__ out1,
                                              unsigned short* __restrict__ zhi,
                                              unsigned short* __restrict__ zlo, int n) {
    constexpr int C = 32;
    int lane = threadIdx.x & 63;
    int node = (blockIdx.x * blockDim.x + threadIdx.x) >> 6;
    if (node >= n) return;

    float xrr  = xr[(size_t)node * 64 + lane];
    float attr = att[lane];
    float m = -INFINITY, d = 0.f, acc = 0.f;

    int e0 = row_ptr[node], e1 = row_ptr[node + 1];
    for (int e = e0; e < e1; ++e) {
        int j = csr[e];
        float v = bf2f(xl[(size_t)j * 64 + lane]);
        float t = v + xrr;
        t = (t > 0.f) ? t : NEG * t;
        t *= attr;
        #pragma unroll
        for (int mask = C / 2; mask >= 1; mask >>= 1)
            t += __shfl_xor(t, mask, 64);
        if (t > m) {                // group-uniform branch
            float sc = __expf(m - t);
            d *= sc; acc *= sc; m = t;
        }
        float p = __expf(t - m);
        d += p;
        acc = fmaf(p, v, acc);
    }
    float o = acc / (d + 1e-16f) + bo[lane];
    // split write: head 0 -> mu, head 1 -> log_var
    int c = lane & 31;
    float* op = (lane < 32) ? out0 : out1;
    op[(size_t)node * C + c] = o;
    // fused reparameterize (lv lives in lane+32)
    float lvv = __shfl(o, lane + 32, 64);
    if (zhi != nullptr && lane < 32) {
        float zc = o + eps[(size_t)node * 32 + lane] * __expf(0.5f * lvv);
        unsigned short h = f2bf(zc);
        zhi[(size_t)node * 32 + lane] = h;
        zlo[(size_t)node * 32 + lane] = f2bf(zc - bf2f(h));
    }
}

// ---------------- concat mu|lv weights into [256,64] / [64] buffers ----------------
__global__ void k_cat(const float* __restrict__ Wlmu, const float* __restrict__ Wllv,
                      const float* __restrict__ Wrmu, const float* __restrict__ Wrlv,
                      const float* __restrict__ blmu, const float* __restrict__ bllv,
                      const float* __restrict__ brmu, const float* __restrict__ brlv,
                      const float* __restrict__ attmu, const float* __restrict__ attlv,
                      const float* __restrict__ bomu, const float* __restrict__ bolv,
                      float* WLC, float* WRC, float* BLC, float* BRC, float* ATTC, float* BOC) {
    int i = blockIdx.x * blockDim.x + threadIdx.x;
    if (i < 256 * 64) {
        int k = i >> 6, c = i & 63;
        WLC[i] = (c < 32) ? Wlmu[k * 32 + c] : Wllv[k * 32 + c - 32];
        WRC[i] = (c < 32) ? Wrmu[k * 32 + c] : Wrlv[k * 32 + c - 32];
    }
    if (i < 64) {
        BLC[i]  = (i < 32) ? blmu[i]  : bllv[i - 32];
        BRC[i]  = (i < 32) ? brmu[i]  : brlv[i - 32];
        ATTC[i] = (i < 32) ? attmu[i] : attlv[i - 32];
        BOC[i]  = (i < 32) ? bomu[i]  : bolv[i - 32];
    }
}

// ---------------- adj = z @ z^T via split-bf16 MFMA (round-6 verified) ----------
constexpr int JTM = 25;   // j-tiles per block; grid.x = 25 -> 625 j-tiles exact

__global__ __launch_bounds__(256) void k_adjm(const unsigned short* __restrict__ zhi,
                                              const unsigned short* __restrict__ zlo,
                                              float* __restrict__ adj, int n) {
    int wave  = threadIdx.x >> 6;
    int l     = threadIdx.x & 63;
    int strip = blockIdx.y * 4 + wave;          // 16-row i-strip
    if (strip * 16 >= n) return;                 // whole-wave exit, no barriers
    int i0   = strip * 16;
    int arow = i0 + (l & 15);
    int koff = (l >> 4) * 8;                     // k-chunk of 8 bf16 = 16B
    bf16x8 a_hi = *(const bf16x8*)(zhi + (size_t)arow * 32 + koff);
    bf16x8 a_lo = *(const bf16x8*)(zlo + (size_t)arow * 32 + koff);
    int crow = i0 + (l >> 4) * 4;                // output row base for this lane

    for (int t = 0; t < JTM; ++t) {
        int j0   = (blockIdx.x * JTM + t) * 16;
        int brow = j0 + (l & 15);
        bf16x8 b_hi = *(const bf16x8*)(zhi + (size_t)brow * 32 + koff);
        bf16x8 b_lo = *(const bf16x8*)(zlo + (size_t)brow * 32 + koff);
        f32x4 acc = {0.f, 0.f, 0.f, 0.f};
        acc = __builtin_amdgcn_mfma_f32_16x16x32_bf16(a_hi, b_hi, acc, 0, 0, 0);
        acc = __builtin_amdgcn_mfma_f32_16x16x32_bf16(a_hi, b_lo, acc, 0, 0, 0);
        acc = __builtin_amdgcn_mfma_f32_16x16x32_bf16(a_lo, b_hi, acc, 0, 0, 0);
        size_t base = (size_t)crow * n + j0 + (l & 15);
        adj[base]                 = acc[0];
        adj[base + (size_t)n]     = acc[1];
        adj[base + (size_t)n * 2] = acc[2];
        adj[base + (size_t)n * 3] = acc[3];
    }
}

// ---------------- fallback adj (round-5 verified VALU path, inline z) ----------
constexpr int JT = 8;
__global__ __launch_bounds__(256) void k_adj_fb(const float* __restrict__ mu,
                                                const float* __restrict__ lv,
                                                const float* __restrict__ eps,
                                                float* __restrict__ adj, int n) {
    __shared__ float Zi[32][68];
    __shared__ float Zj[32][68];
    int tid = threadIdx.x;
    int tx = tid & 15, ty = tid >> 4;
    int i0 = blockIdx.y * 64;
    int r = tid >> 2, kq = (tid & 3) * 8;

    auto load8 = [&](int row, float4& a, float4& b) {
        a = make_float4(0.f, 0.f, 0.f, 0.f);
        b = make_float4(0.f, 0.f, 0.f, 0.f);
        if (row < n) {
            float4 m0 = *(const float4*)&mu[row * 32 + kq];
            float4 l0 = *(const float4*)&lv[row * 32 + kq];
            float4 e0 = *(const float4*)&eps[row * 32 + kq];
            float4 m1 = *(const float4*)&mu[row * 32 + kq + 4];
            float4 l1 = *(const float4*)&lv[row * 32 + kq + 4];
            float4 e1 = *(const float4*)&eps[row * 32 + kq + 4];
            a.x = m0.x + e0.x * __expf(0.5f * l0.x);
            a.y = m0.y + e0.y * __expf(0.5f * l0.y);
            a.z = m0.z + e0.z * __expf(0.5f * l0.z);
            a.w = m0.w + e0.w * __expf(0.5f * l0.w);
            b.x = m1.x + e1.x * __expf(0.5f * l1.x);
            b.y = m1.y + e1.y * __expf(0.5f * l1.y);
            b.z = m1.z + e1.z * __expf(0.5f * l1.z);
            b.w = m1.w + e1.w * __expf(0.5f * l1.w);
        }
    };

    {
        float4 a, b;
        load8(i0 + r, a, b);
        Zi[kq + 0][r] = a.x; Zi[kq + 1][r] = a.y; Zi[kq + 2][r] = a.z; Zi[kq + 3][r] = a.w;
        Zi[kq + 4][r] = b.x; Zi[kq + 5][r] = b.y; Zi[kq + 6][r] = b.z; Zi[kq + 7][r] = b.w;
    }
    __syncthreads();
    float4 af[32];
    #pragma unroll
    for (int k = 0; k < 32; ++k) af[k] = *(const float4*)&Zi[k][ty * 4];

    for (int jt = 0; jt < JT; ++jt) {
        int j0 = (blockIdx.x * JT + jt) * 64;
        if (j0 >= n) break;
        {
            float4 a, b;
            load8(j0 + r, a, b);
            __syncthreads();
            Zj[kq + 0][r] = a.x; Zj[kq + 1][r] = a.y; Zj[kq + 2][r] = a.z; Zj[kq + 3][r] = a.w;
            Zj[kq + 4][r] = b.x; Zj[kq + 5][r] = b.y; Zj[kq + 6][r] = b.z; Zj[kq + 7][r] = b.w;
            __syncthreads();
        }
        float acc[4][4] = {};
        #pragma unroll
        for (int k = 0; k < 32; ++k) {
            float4 b = *(const float4*)&Zj[k][tx * 4];
            float av[4] = {af[k].x, af[k].y, af[k].z, af[k].w};
            float bv[4] = {b.x, b.y, b.z, b.w};
            #pragma unroll
            for (int i2 = 0; i2 < 4; ++i2)
                #pragma unroll
                for (int j2 = 0; j2 < 4; ++j2)
                    acc[i2][j2] = fmaf(av[i2], bv[j2], acc[i2][j2]);
        }
        int col = j0 + tx * 4;
        if (col < n) {
            #pragma unroll
            for (int i2 = 0; i2 < 4; ++i2) {
                int row = i0 + ty * 4 + i2;
                if (row < n) {
                    float4 o = {acc[i2][0], acc[i2][1], acc[i2][2], acc[i2][3]};
                    *(float4*)&adj[(size_t)row * n + col] = o;
                }
            }
        }
    }
}

// ---------------- launcher ----------------
extern "C" void kernel_launch(void* const* d_in, const int* in_sizes, int n_in,
                              void* d_out, int out_size, void* d_ws, size_t ws_size,
                              hipStream_t stream) {
    const float* x      = (const float*)d_in[0];
    const int*   edges  = (const int*)d_in[1];
    const float* eps    = (const float*)d_in[2];
    const float* Wl0 = (const float*)d_in[3];
    const float* bl0 = (const float*)d_in[4];
    const float* Wr0 = (const float*)d_in[5];
    const float* br0 = (const float*)d_in[6];
    const float* at0 = (const float*)d_in[7];
    const float* bo0 = (const float*)d_in[8];
    const float* Wl1 = (const float*)d_in[9];
    const float* bl1 = (const float*)d_in[10];
    const float* Wr1 = (const float*)d_in[11];
    const float* br1 = (const float*)d_in[12];
    const float* at1 = (const float*)d_in[13];
    const float* bo1 = (const float*)d_in[14];
    const float* Wlmu = (const float*)d_in[15];
    const float* blmu = (const float*)d_in[16];
    const float* Wrmu = (const float*)d_in[17];
    const float* brmu = (const float*)d_in[18];
    const float* atmu = (const float*)d_in[19];
    const float* bomu = (const float*)d_in[20];
    const float* Wllv = (const float*)d_in[21];
    const float* bllv = (const float*)d_in[22];
    const float* Wrlv = (const float*)d_in[23];
    const float* brlv = (const float*)d_in[24];
    const float* atlv = (const float*)d_in[25];
    const float* bolv = (const float*)d_in[26];

    float* base   = (float*)d_out;
    float* adj    = base;
    float* mu_out = base + (size_t)Nn * Nn;
    float* lv_out = mu_out + (size_t)Nn * 32;

    unsigned short* XLB  = (unsigned short*)(base + OFF_XL);   // bf16 [N,256]
    float* XR  = base + OFF_XR;
    float* H   = base + OFF_H;
    unsigned short* XSLB = (unsigned short*)(base + OFF_XSL);  // bf16 [N,64]
    float* XSR = base + OFF_XSR;
    float* WLC = base + OFF_WLC;
    float* WRC = base + OFF_WRC;
    float* BLC = base + OFF_BLC;
    float* BRC = base + OFF_BRC;
    float* ATT = base + OFF_ATT;
    float* BOC = base + OFF_BOC;
    int* ib  = (int*)(base + OFF_INT);
    int* deg = ib + I_DEG;
    int* row = ib + I_ROW;
    int* cur = ib + I_CUR;
    int* csr = ib + I_CSR;
    const int* srcp = edges;
    const int* dstp = edges + Ed;

    size_t need = (size_t)Nn * 32 * 2 * sizeof(unsigned short);
    unsigned short* zhi = (ws_size >= need) ? (unsigned short*)d_ws : nullptr;
    unsigned short* zlo = zhi ? zhi + (size_t)Nn * 32 : nullptr;

    // CSR build (src/dst shared by all 4 GAT layers)
    k_init_deg<<<(Nn + 255) / 256, 256, 0, stream>>>(deg, Nn);
    k_count<<<(Ed + 255) / 256, 256, 0, stream>>>(dstp, deg, Ed);
    k_scan<<<1, 256, 0, stream>>>(deg, row, cur, Nn);
    k_scatter<<<(Ed + Nn + 255) / 256, 256, 0, stream>>>(srcp, dstp, cur, csr, Ed, Nn);

    dim3 g4(79, 4), g1(79, 1);   // 128-row tiles: 79*128 = 10112 >= 10000
    // layer 0  (fused L/R GEMM; XL bf16, XR f32)
    k_gemm2<256><<<g4, 256, 0, stream>>>(x, Wl0, bl0, XLB, Wr0, br0, XR, Nn);
    k_gat4<true><<<2500, 256, 0, stream>>>(XLB, XR, at0, bo0, row, csr, H, Nn);
    // layer 1
    k_gemm2<256><<<g4, 256, 0, stream>>>(H, Wl1, bl1, XLB, Wr1, br1, XR, Nn);
    k_gat4<true><<<2500, 256, 0, stream>>>(XLB, XR, at1, bo1, row, csr, H, Nn);
    // mu / log_var (fused as 2 independent heads of 32) + fused reparameterize
    k_cat<<<64, 256, 0, stream>>>(Wlmu, Wllv, Wrmu, Wrlv, blmu, bllv, brmu, brlv,
                                  atmu, atlv, bomu, bolv, WLC, WRC, BLC, BRC, ATT, BOC);
    k_gemm2<64><<<g1, 256, 0, stream>>>(H, WLC, BLC, XSLB, WRC, BRC, XSR, Nn);
    k_gatz<<<2500, 256, 0, stream>>>(XSLB, XSR, ATT, BOC, row, csr, eps,
                                     mu_out, lv_out, zhi, zlo, Nn);

    // decode
    if (zhi) {
        dim3 ga(25, 157);   // 25*JTM=625 j-tiles exact; 157*4=628 i-strips (>=625)
        k_adjm<<<ga, 256, 0, stream>>>(zhi, zlo, adj, Nn);
    } else {
        dim3 ga(20, 157);
        k_adj_fb<<<ga, 256, 0, stream>>>(mu_out, lv_out, eps, adj, Nn);
    }
}

// Round 13
// 396.564 us; speedup vs baseline: 1.0927x; 1.0927x over previous
//
#include <hip/hip_runtime.h>
#include <hip/hip_bf16.h>
#include <math.h>

// ---------------- problem constants ----------------
constexpr int Nn  = 10000;     // nodes
constexpr int Ed  = 320000;    // edges (before self-loops)
constexpr int DIN = 256;
constexpr float NEG = 0.2f;    // leaky-relu slope

// ---------------- scratch layout inside d_out (float offsets) ----------------
// d_out = [adj 1e8][mu 320000][log_var 320000]. The adj region is free scratch
// until k_adjm, which fully overwrites it (round-3 lesson: nothing may live in
// the adj region once k_adjm starts).
constexpr size_t OFF_XL  = 0;          // [N,256] bf16 (gather operand)
constexpr size_t OFF_XR  = 2560000;    // [N,256] f32
constexpr size_t OFF_H   = 5120000;    // [N,256] f32
constexpr size_t OFF_XSL = 7680000;    // [N,64]  bf16 (xl_mu | xl_lv)
constexpr size_t OFF_XSR = 8320000;    // [N,64]  f32
constexpr size_t OFF_INT = 9000000;    // int area base
constexpr int I_DEG = 0;               // [N]
constexpr int I_ROW = 16384;           // [N+1]
constexpr int I_CUR = 32768;           // [N]
constexpr int I_CSR = 49152;           // [E+N]
static_assert(OFF_INT + (I_CSR + Ed + Nn + 4) < 100000000, "scratch fits in adj region");

// ---------------- bf16 helpers (RNE) ----------------
__device__ __forceinline__ unsigned short f2bf(float x) {
    unsigned int u = __float_as_uint(x);
    unsigned int r = (u + 0x7FFFu + ((u >> 16) & 1u)) >> 16;
    return (unsigned short)r;
}
__device__ __forceinline__ float bf2f(unsigned short b) {
    return __uint_as_float(((unsigned int)b) << 16);
}

typedef short bf16x8 __attribute__((ext_vector_type(8)));
typedef float f32x4  __attribute__((ext_vector_type(4)));

// ---------------- CSR build ----------------
__global__ void k_init_deg(int* deg, int n) {
    int i = blockIdx.x * blockDim.x + threadIdx.x;
    if (i < n) deg[i] = 1;   // self-loop
}

__global__ void k_count(const int* __restrict__ dst, int* deg, int e) {
    int i = blockIdx.x * blockDim.x + threadIdx.x;
    if (i < e) atomicAdd(&deg[dst[i]], 1);
}

__global__ void k_scan(const int* __restrict__ deg, int* row_ptr, int* cursor, int n) {
    __shared__ int sums[256];
    int t = threadIdx.x;
    int chunk = (n + 255) / 256;
    int start = t * chunk, end = min(start + chunk, n);
    int s = 0;
    for (int i = start; i < end; ++i) s += deg[i];
    sums[t] = s;
    __syncthreads();
    for (int off = 1; off < 256; off <<= 1) {
        int v = (t >= off) ? sums[t - off] : 0;
        __syncthreads();
        sums[t] += v;
        __syncthreads();
    }
    int run = sums[t] - s;  // exclusive prefix
    for (int i = start; i < end; ++i) { row_ptr[i] = run; cursor[i] = run; run += deg[i]; }
    if (t == 255) row_ptr[n] = sums[255];
}

__global__ void k_scatter(const int* __restrict__ src, const int* __restrict__ dst,
                          int* cursor, int* csr, int e, int n) {
    int i = blockIdx.x * blockDim.x + threadIdx.x;
    if (i < e) {
        int d = dst[i];
        int pos = atomicAdd(&cursor[d], 1);
        csr[pos] = src[i];
    } else if (i < e + n) {
        int v = i - e;                        // self-loop
        int pos = atomicAdd(&cursor[v], 1);
        csr[pos] = v;
    }
}

// ---------------- fused dual GEMM: outL/outR = A @ {WL,WR} + bias -------------
// Round-9/11-verified: 64-row tile, 4x4 micro-tile, A-tile staged ONCE and
// reused for both weight matrices. outL bf16 (GAT gather operand), outR f32.
// SPLIT=true: WL/WR and biases are given as {mu,lv} halves ([256,32] each,
// virtually concatenated to NC=64). wnb is a multiple of 8 and col=tx*4, so
// every staged float4 / bias quad lies entirely within one half.
template <int NC, bool SPLIT>
__global__ __launch_bounds__(256) void k_gemm2(const float* __restrict__ A,
                                               const float* __restrict__ WLa,
                                               const float* __restrict__ WLb,
                                               const float* __restrict__ bLa,
                                               const float* __restrict__ bLb,
                                               unsigned short* __restrict__ outL,
                                               const float* __restrict__ WRa,
                                               const float* __restrict__ WRb,
                                               const float* __restrict__ bRa,
                                               const float* __restrict__ bRb,
                                               float* __restrict__ outR,
                                               int M) {
    constexpr int K = 256;
    __shared__ float As[32][68];    // [k][m], padded stride 68
    __shared__ float WsL[32][64];   // [k][n]
    __shared__ float WsR[32][64];
    int tid = threadIdx.x;
    int tx = tid & 15, ty = tid >> 4;
    int m0 = blockIdx.x * 64, n0 = blockIdx.y * 64;
    float accL[4][4] = {}, accR[4][4] = {};
    int am = tid >> 2, akb = (tid & 3) * 8;       // A-tile: row am, k-chunk akb..+7
    int wk = tid >> 3, wnb = (tid & 7) * 8;       // W-tile: k-row wk, n-chunk wnb..+7
    const bool arow_ok = (m0 + am) < M;
    const float* Aptr = A + (size_t)(m0 + am) * K + akb;
    const float* WLptr;
    const float* WRptr;
    if constexpr (SPLIT) {
        // NC == 64, n0 == 0; halves are [256,32] row-major
        WLptr = (wnb < 32) ? WLa + (size_t)wk * 32 + wnb : WLb + (size_t)wk * 32 + (wnb - 32);
        WRptr = (wnb < 32) ? WRa + (size_t)wk * 32 + wnb : WRb + (size_t)wk * 32 + (wnb - 32);
    } else {
        WLptr = WLa + (size_t)wk * NC + n0 + wnb;
        WRptr = WRa + (size_t)wk * NC + n0 + wnb;
    }
    constexpr int WSTRIDE = SPLIT ? 32 : NC;      // row stride of the source W

    for (int k0 = 0; k0 < K; k0 += 32) {
        float4 a0 = {0, 0, 0, 0}, a1 = {0, 0, 0, 0};
        if (arow_ok) {
            a0 = *(const float4*)(Aptr + k0);
            a1 = *(const float4*)(Aptr + k0 + 4);
        }
        float4 wl0 = *(const float4*)(WLptr + (size_t)k0 * WSTRIDE);
        float4 wl1 = *(const float4*)(WLptr + (size_t)k0 * WSTRIDE + 4);
        float4 wr0 = *(const float4*)(WRptr + (size_t)k0 * WSTRIDE);
        float4 wr1 = *(const float4*)(WRptr + (size_t)k0 * WSTRIDE + 4);
        __syncthreads();   // protect previous iteration's LDS reads
        As[akb + 0][am] = a0.x; As[akb + 1][am] = a0.y; As[akb + 2][am] = a0.z; As[akb + 3][am] = a0.w;
        As[akb + 4][am] = a1.x; As[akb + 5][am] = a1.y; As[akb + 6][am] = a1.z; As[akb + 7][am] = a1.w;
        *(float4*)&WsL[wk][wnb]     = wl0;
        *(float4*)&WsL[wk][wnb + 4] = wl1;
        *(float4*)&WsR[wk][wnb]     = wr0;
        *(float4*)&WsR[wk][wnb + 4] = wr1;
        __syncthreads();
        #pragma unroll
        for (int k = 0; k < 32; ++k) {
            float4 a  = *(const float4*)&As[k][ty * 4];
            float4 bl = *(const float4*)&WsL[k][tx * 4];
            float4 br = *(const float4*)&WsR[k][tx * 4];
            float av[4]  = {a.x, a.y, a.z, a.w};
            float blv[4] = {bl.x, bl.y, bl.z, bl.w};
            float brv[4] = {br.x, br.y, br.z, br.w};
            #pragma unroll
            for (int i2 = 0; i2 < 4; ++i2)
                #pragma unroll
                for (int j2 = 0; j2 < 4; ++j2) {
                    accL[i2][j2] = fmaf(av[i2], blv[j2], accL[i2][j2]);
                    accR[i2][j2] = fmaf(av[i2], brv[j2], accR[i2][j2]);
                }
        }
    }
    int colq = n0 + tx * 4;   // multiple of 4; within one half when SPLIT
    float bL[4], bR[4];
    #pragma unroll
    for (int q = 0; q < 4; ++q) {
        int col = colq + q;
        if constexpr (SPLIT) {
            bL[q] = (col < 32) ? bLa[col] : bLb[col - 32];
            bR[q] = (col < 32) ? bRa[col] : bRb[col - 32];
        } else {
            bL[q] = bLa[col];
            bR[q] = bRa[col];
        }
    }
    #pragma unroll
    for (int i2 = 0; i2 < 4; ++i2) {
        int row = m0 + ty * 4 + i2;
        if (row < M) {
            // L (bf16)
            ushort4 s;
            s.x = f2bf(accL[i2][0] + bL[0]);
            s.y = f2bf(accL[i2][1] + bL[1]);
            s.z = f2bf(accL[i2][2] + bL[2]);
            s.w = f2bf(accL[i2][3] + bL[3]);
            *(ushort4*)&outL[(size_t)row * NC + colq] = s;
            // R (f32)
            float4 o;
            o.x = accR[i2][0] + bR[0];
            o.y = accR[i2][1] + bR[1];
            o.z = accR[i2][2] + bR[2];
            o.w = accR[i2][3] + bR[3];
            *(float4*)&outR[(size_t)row * NC + colq] = o;
        }
    }
}

// ---------------- GATv2 aggregation, F=256 H=4 C=64 (lane = 4 channels) ----------
// xl is bf16 (512B/edge gather). Round-11-verified 4-edge-unroll structure.
__device__ __forceinline__ float lrelu(float x) { return x > 0.f ? x : NEG * x; }

template <bool DO_ELU>
__global__ __launch_bounds__(256) void k_gat4(const unsigned short* __restrict__ xl,
                                              const float* __restrict__ xr,
                                              const float* __restrict__ att,
                                              const float* __restrict__ bo,
                                              const int* __restrict__ row_ptr,
                                              const int* __restrict__ csr,
                                              float* __restrict__ out, int n) {
    int lane = threadIdx.x & 63;
    int node = (blockIdx.x * blockDim.x + threadIdx.x) >> 6;
    if (node >= n) return;
    int f = lane * 4;
    float4 xrr  = *(const float4*)&xr[(size_t)node * 256 + f];
    float4 attr = *(const float4*)&att[f];
    float m = -INFINITY, d = 0.f;
    float4 acc = {0.f, 0.f, 0.f, 0.f};

    int e0 = row_ptr[node], e1 = row_ptr[node + 1];
    int e = e0;
    for (; e + 3 < e1; e += 4) {
        int ja = csr[e],     jb = csr[e + 1];
        int jc = csr[e + 2], jd = csr[e + 3];
        ushort4 ua = *(const ushort4*)&xl[(size_t)ja * 256 + f];
        ushort4 ub = *(const ushort4*)&xl[(size_t)jb * 256 + f];
        ushort4 uc = *(const ushort4*)&xl[(size_t)jc * 256 + f];
        ushort4 ud = *(const ushort4*)&xl[(size_t)jd * 256 + f];
        float4 va = {bf2f(ua.x), bf2f(ua.y), bf2f(ua.z), bf2f(ua.w)};
        float4 vb = {bf2f(ub.x), bf2f(ub.y), bf2f(ub.z), bf2f(ub.w)};
        float4 vc = {bf2f(uc.x), bf2f(uc.y), bf2f(uc.z), bf2f(uc.w)};
        float4 vd = {bf2f(ud.x), bf2f(ud.y), bf2f(ud.z), bf2f(ud.w)};
        float ta = attr.x * lrelu(va.x + xrr.x) + attr.y * lrelu(va.y + xrr.y)
                 + attr.z * lrelu(va.z + xrr.z) + attr.w * lrelu(va.w + xrr.w);
        float tb = attr.x * lrelu(vb.x + xrr.x) + attr.y * lrelu(vb.y + xrr.y)
                 + attr.z * lrelu(vb.z + xrr.z) + attr.w * lrelu(vb.w + xrr.w);
        float tc = attr.x * lrelu(vc.x + xrr.x) + attr.y * lrelu(vc.y + xrr.y)
                 + attr.z * lrelu(vc.z + xrr.z) + attr.w * lrelu(vc.w + xrr.w);
        float td = attr.x * lrelu(vd.x + xrr.x) + attr.y * lrelu(vd.y + xrr.y)
                 + attr.z * lrelu(vd.z + xrr.z) + attr.w * lrelu(vd.w + xrr.w);
        #pragma unroll
        for (int mask = 1; mask <= 8; mask <<= 1) {
            ta += __shfl_xor(ta, mask, 64);
            tb += __shfl_xor(tb, mask, 64);
            tc += __shfl_xor(tc, mask, 64);
            td += __shfl_xor(td, mask, 64);
        }
        float mn = fmaxf(fmaxf(m, fmaxf(ta, tb)), fmaxf(tc, td));
        float sc = __expf(m - mn);         // 1 when m == mn; 0 when m == -inf
        float pa = __expf(ta - mn), pb = __expf(tb - mn);
        float pc = __expf(tc - mn), pd = __expf(td - mn);
        d = d * sc + pa + pb + pc + pd;
        acc.x = acc.x * sc + pa * va.x + pb * vb.x + pc * vc.x + pd * vd.x;
        acc.y = acc.y * sc + pa * va.y + pb * vb.y + pc * vc.y + pd * vd.y;
        acc.z = acc.z * sc + pa * va.z + pb * vb.z + pc * vc.z + pd * vd.z;
        acc.w = acc.w * sc + pa * va.w + pb * vb.w + pc * vc.w + pd * vd.w;
        m = mn;
    }
    for (; e < e1; ++e) {
        int j = csr[e];
        ushort4 u = *(const ushort4*)&xl[(size_t)j * 256 + f];
        float4 v = {bf2f(u.x), bf2f(u.y), bf2f(u.z), bf2f(u.w)};
        float t = attr.x * lrelu(v.x + xrr.x) + attr.y * lrelu(v.y + xrr.y)
                + attr.z * lrelu(v.z + xrr.z) + attr.w * lrelu(v.w + xrr.w);
        #pragma unroll
        for (int mask = 1; mask <= 8; mask <<= 1) t += __shfl_xor(t, mask, 64);
        float mn = fmaxf(m, t);
        float sc = __expf(m - mn), p = __expf(t - mn);
        d = d * sc + p;
        acc.x = acc.x * sc + p * v.x;
        acc.y = acc.y * sc + p * v.y;
        acc.z = acc.z * sc + p * v.z;
        acc.w = acc.w * sc + p * v.w;
        m = mn;
    }
    float inv = 1.f / (d + 1e-16f);
    float4 bo4 = *(const float4*)&bo[f];
    float4 o;
    o.x = acc.x * inv + bo4.x;
    o.y = acc.y * inv + bo4.y;
    o.z = acc.z * inv + bo4.z;
    o.w = acc.w * inv + bo4.w;
    if (DO_ELU) {
        o.x = o.x > 0.f ? o.x : expm1f(o.x);
        o.y = o.y > 0.f ? o.y : expm1f(o.y);
        o.z = o.z > 0.f ? o.z : expm1f(o.z);
        o.w = o.w > 0.f ? o.w : expm1f(o.w);
    }
    *(float4*)&out[(size_t)node * 256 + f] = o;
}

// ---------------- mu|lv GAT (H=2,C=32,F=64) + fused reparameterize ------------
// Round-9-verified. Lanes 0-31 hold mu_c, lanes 32-63 hold lv_c; shfl brings
// lv down; lane<32 computes z and writes split-bf16 zhi/zlo (skipped if null).
// att/bo selected inline from the mu/lv arrays (k_cat eliminated).
__global__ __launch_bounds__(256) void k_gatz(const unsigned short* __restrict__ xl,
                                              const float* __restrict__ xr,
                                              const float* __restrict__ atmu,
                                              const float* __restrict__ atlv,
                                              const float* __restrict__ bomu,
                                              const float* __restrict__ bolv,
                                              const int* __restrict__ row_ptr,
                                              const int* __restrict__ csr,
                                              const float* __restrict__ eps,
                                              float* __restrict__ out0,
                                              float* __restrict__ out1,
                                              unsigned short* __restrict__ zhi,
                                              unsigned short* __restrict__ zlo, int n) {
    constexpr int C = 32;
    int lane = threadIdx.x & 63;
    int node = (blockIdx.x * blockDim.x + threadIdx.x) >> 6;
    if (node >= n) return;

    float xrr  = xr[(size_t)node * 64 + lane];
    float attr = (lane < 32) ? atmu[lane] : atlv[lane - 32];
    float m = -INFINITY, d = 0.f, acc = 0.f;

    int e0 = row_ptr[node], e1 = row_ptr[node + 1];
    for (int e = e0; e < e1; ++e) {
        int j = csr[e];
        float v = bf2f(xl[(size_t)j * 64 + lane]);
        float t = v + xrr;
        t = (t > 0.f) ? t : NEG * t;
        t *= attr;
        #pragma unroll
        for (int mask = C / 2; mask >= 1; mask >>= 1)
            t += __shfl_xor(t, mask, 64);
        if (t > m) {                // group-uniform branch
            float sc = __expf(m - t);
            d *= sc; acc *= sc; m = t;
        }
        float p = __expf(t - m);
        d += p;
        acc = fmaf(p, v, acc);
    }
    float bov = (lane < 32) ? bomu[lane] : bolv[lane - 32];
    float o = acc / (d + 1e-16f) + bov;
    // split write: head 0 -> mu, head 1 -> log_var
    int c = lane & 31;
    float* op = (lane < 32) ? out0 : out1;
    op[(size_t)node * C + c] = o;
    // fused reparameterize (lv lives in lane+32)
    float lvv = __shfl(o, lane + 32, 64);
    if (zhi != nullptr && lane < 32) {
        float zc = o + eps[(size_t)node * 32 + lane] * __expf(0.5f * lvv);
        unsigned short h = f2bf(zc);
        zhi[(size_t)node * 32 + lane] = h;
        zlo[(size_t)node * 32 + lane] = f2bf(zc - bf2f(h));
    }
}

// ---------------- adj = z @ z^T via split-bf16 MFMA (round-6 verified) ----------
constexpr int JTM = 25;   // j-tiles per block; grid.x = 25 -> 625 j-tiles exact

__global__ __launch_bounds__(256) void k_adjm(const unsigned short* __restrict__ zhi,
                                              const unsigned short* __restrict__ zlo,
                                              float* __restrict__ adj, int n) {
    int wave  = threadIdx.x >> 6;
    int l     = threadIdx.x & 63;
    int strip = blockIdx.y * 4 + wave;          // 16-row i-strip
    if (strip * 16 >= n) return;                 // whole-wave exit, no barriers
    int i0   = strip * 16;
    int arow = i0 + (l & 15);
    int koff = (l >> 4) * 8;                     // k-chunk of 8 bf16 = 16B
    bf16x8 a_hi = *(const bf16x8*)(zhi + (size_t)arow * 32 + koff);
    bf16x8 a_lo = *(const bf16x8*)(zlo + (size_t)arow * 32 + koff);
    int crow = i0 + (l >> 4) * 4;                // output row base for this lane

    for (int t = 0; t < JTM; ++t) {
        int j0   = (blockIdx.x * JTM + t) * 16;
        int brow = j0 + (l & 15);
        bf16x8 b_hi = *(const bf16x8*)(zhi + (size_t)brow * 32 + koff);
        bf16x8 b_lo = *(const bf16x8*)(zlo + (size_t)brow * 32 + koff);
        f32x4 acc = {0.f, 0.f, 0.f, 0.f};
        acc = __builtin_amdgcn_mfma_f32_16x16x32_bf16(a_hi, b_hi, acc, 0, 0, 0);
        acc = __builtin_amdgcn_mfma_f32_16x16x32_bf16(a_hi, b_lo, acc, 0, 0, 0);
        acc = __builtin_amdgcn_mfma_f32_16x16x32_bf16(a_lo, b_hi, acc, 0, 0, 0);
        size_t base = (size_t)crow * n + j0 + (l & 15);
        adj[base]                 = acc[0];
        adj[base + (size_t)n]     = acc[1];
        adj[base + (size_t)n * 2] = acc[2];
        adj[base + (size_t)n * 3] = acc[3];
    }
}

// ---------------- fallback adj (round-5 verified VALU path, inline z) ----------
constexpr int JT = 8;
__global__ __launch_bounds__(256) void k_adj_fb(const float* __restrict__ mu,
                                                const float* __restrict__ lv,
                                                const float* __restrict__ eps,
                                                float* __restrict__ adj, int n) {
    __shared__ float Zi[32][68];
    __shared__ float Zj[32][68];
    int tid = threadIdx.x;
    int tx = tid & 15, ty = tid >> 4;
    int i0 = blockIdx.y * 64;
    int r = tid >> 2, kq = (tid & 3) * 8;

    auto load8 = [&](int row, float4& a, float4& b) {
        a = make_float4(0.f, 0.f, 0.f, 0.f);
        b = make_float4(0.f, 0.f, 0.f, 0.f);
        if (row < n) {
            float4 m0 = *(const float4*)&mu[row * 32 + kq];
            float4 l0 = *(const float4*)&lv[row * 32 + kq];
            float4 e0 = *(const float4*)&eps[row * 32 + kq];
            float4 m1 = *(const float4*)&mu[row * 32 + kq + 4];
            float4 l1 = *(const float4*)&lv[row * 32 + kq + 4];
            float4 e1 = *(const float4*)&eps[row * 32 + kq + 4];
            a.x = m0.x + e0.x * __expf(0.5f * l0.x);
            a.y = m0.y + e0.y * __expf(0.5f * l0.y);
            a.z = m0.z + e0.z * __expf(0.5f * l0.z);
            a.w = m0.w + e0.w * __expf(0.5f * l0.w);
            b.x = m1.x + e1.x * __expf(0.5f * l1.x);
            b.y = m1.y + e1.y * __expf(0.5f * l1.y);
            b.z = m1.z + e1.z * __expf(0.5f * l1.z);
            b.w = m1.w + e1.w * __expf(0.5f * l1.w);
        }
    };

    {
        float4 a, b;
        load8(i0 + r, a, b);
        Zi[kq + 0][r] = a.x; Zi[kq + 1][r] = a.y; Zi[kq + 2][r] = a.z; Zi[kq + 3][r] = a.w;
        Zi[kq + 4][r] = b.x; Zi[kq + 5][r] = b.y; Zi[kq + 6][r] = b.z; Zi[kq + 7][r] = b.w;
    }
    __syncthreads();
    float4 af[32];
    #pragma unroll
    for (int k = 0; k < 32; ++k) af[k] = *(const float4*)&Zi[k][ty * 4];

    for (int jt = 0; jt < JT; ++jt) {
        int j0 = (blockIdx.x * JT + jt) * 64;
        if (j0 >= n) break;
        {
            float4 a, b;
            load8(j0 + r, a, b);
            __syncthreads();
            Zj[kq + 0][r] = a.x; Zj[kq + 1][r] = a.y; Zj[kq + 2][r] = a.z; Zj[kq + 3][r] = a.w;
            Zj[kq + 4][r] = b.x; Zj[kq + 5][r] = b.y; Zj[kq + 6][r] = b.z; Zj[kq + 7][r] = b.w;
            __syncthreads();
        }
        float acc[4][4] = {};
        #pragma unroll
        for (int k = 0; k < 32; ++k) {
            float4 b = *(const float4*)&Zj[k][tx * 4];
            float av[4] = {af[k].x, af[k].y, af[k].z, af[k].w};
            float bv[4] = {b.x, b.y, b.z, b.w};
            #pragma unroll
            for (int i2 = 0; i2 < 4; ++i2)
                #pragma unroll
                for (int j2 = 0; j2 < 4; ++j2)
                    acc[i2][j2] = fmaf(av[i2], bv[j2], acc[i2][j2]);
        }
        int col = j0 + tx * 4;
        if (col < n) {
            #pragma unroll
            for (int i2 = 0; i2 < 4; ++i2) {
                int row = i0 + ty * 4 + i2;
                if (row < n) {
                    float4 o = {acc[i2][0], acc[i2][1], acc[i2][2], acc[i2][3]};
                    *(float4*)&adj[(size_t)row * n + col] = o;
                }
            }
        }
    }
}

// ---------------- launcher ----------------
extern "C" void kernel_launch(void* const* d_in, const int* in_sizes, int n_in,
                              void* d_out, int out_size, void* d_ws, size_t ws_size,
                              hipStream_t stream) {
    const float* x      = (const float*)d_in[0];
    const int*   edges  = (const int*)d_in[1];
    const float* eps    = (const float*)d_in[2];
    const float* Wl0 = (const float*)d_in[3];
    const float* bl0 = (const float*)d_in[4];
    const float* Wr0 = (const float*)d_in[5];
    const float* br0 = (const float*)d_in[6];
    const float* at0 = (const float*)d_in[7];
    const float* bo0 = (const float*)d_in[8];
    const float* Wl1 = (const float*)d_in[9];
    const float* bl1 = (const float*)d_in[10];
    const float* Wr1 = (const float*)d_in[11];
    const float* br1 = (const float*)d_in[12];
    const float* at1 = (const float*)d_in[13];
    const float* bo1 = (const float*)d_in[14];
    const float* Wlmu = (const float*)d_in[15];
    const float* blmu = (const float*)d_in[16];
    const float* Wrmu = (const float*)d_in[17];
    const float* brmu = (const float*)d_in[18];
    const float* atmu = (const float*)d_in[19];
    const float* bomu = (const float*)d_in[20];
    const float* Wllv = (const float*)d_in[21];
    const float* bllv = (const float*)d_in[22];
    const float* Wrlv = (const float*)d_in[23];
    const float* brlv = (const float*)d_in[24];
    const float* atlv = (const float*)d_in[25];
    const float* bolv = (const float*)d_in[26];

    float* base   = (float*)d_out;
    float* adj    = base;
    float* mu_out = base + (size_t)Nn * Nn;
    float* lv_out = mu_out + (size_t)Nn * 32;

    unsigned short* XLB  = (unsigned short*)(base + OFF_XL);   // bf16 [N,256]
    float* XR  = base + OFF_XR;
    float* H   = base + OFF_H;
    unsigned short* XSLB = (unsigned short*)(base + OFF_XSL);  // bf16 [N,64]
    float* XSR = base + OFF_XSR;
    int* ib  = (int*)(base + OFF_INT);
    int* deg = ib + I_DEG;
    int* row = ib + I_ROW;
    int* cur = ib + I_CUR;
    int* csr = ib + I_CSR;
    const int* srcp = edges;
    const int* dstp = edges + Ed;

    size_t need = (size_t)Nn * 32 * 2 * sizeof(unsigned short);
    unsigned short* zhi = (ws_size >= need) ? (unsigned short*)d_ws : nullptr;
    unsigned short* zlo = zhi ? zhi + (size_t)Nn * 32 : nullptr;

    // CSR build (src/dst shared by all 4 GAT layers)
    k_init_deg<<<(Nn + 255) / 256, 256, 0, stream>>>(deg, Nn);
    k_count<<<(Ed + 255) / 256, 256, 0, stream>>>(dstp, deg, Ed);
    k_scan<<<1, 256, 0, stream>>>(deg, row, cur, Nn);
    k_scatter<<<(Ed + Nn + 255) / 256, 256, 0, stream>>>(srcp, dstp, cur, csr, Ed, Nn);

    dim3 g4(157, 4), g1(157, 1);
    // layer 0  (fused L/R GEMM; XL bf16, XR f32)
    k_gemm2<256, false><<<g4, 256, 0, stream>>>(x, Wl0, nullptr, bl0, nullptr, XLB,
                                                Wr0, nullptr, br0, nullptr, XR, Nn);
    k_gat4<true><<<2500, 256, 0, stream>>>(XLB, XR, at0, bo0, row, csr, H, Nn);
    // layer 1
    k_gemm2<256, false><<<g4, 256, 0, stream>>>(H, Wl1, nullptr, bl1, nullptr, XLB,
                                                Wr1, nullptr, br1, nullptr, XR, Nn);
    k_gat4<true><<<2500, 256, 0, stream>>>(XLB, XR, at1, bo1, row, csr, H, Nn);
    // mu / log_var (fused 2-head layer; weights/biases read directly as halves)
    k_gemm2<64, true><<<g1, 256, 0, stream>>>(H, Wlmu, Wllv, blmu, bllv, XSLB,
                                              Wrmu, Wrlv, brmu, brlv, XSR, Nn);
    k_gatz<<<2500, 256, 0, stream>>>(XSLB, XSR, atmu, atlv, bomu, bolv, row, csr, eps,
                                     mu_out, lv_out, zhi, zlo, Nn);

    // decode
    if (zhi) {
        dim3 ga(25, 157);   // 25*JTM=625 j-tiles exact; 157*4=628 i-strips (>=625)
        k_adjm<<<ga, 256, 0, stream>>>(zhi, zlo, adj, Nn);
    } else {
        dim3 ga(20, 157);
        k_adj_fb<<<ga, 256, 0, stream>>>(mu_out, lv_out, eps, adj, Nn);
    }
}